// Round 7
// baseline (648.290 us; speedup 1.0000x reference)
//
#include <hip/hip_runtime.h>
#include <hip/hip_bf16.h>
#include <math.h>

typedef __bf16 bf16;
typedef bf16  bf16x8 __attribute__((ext_vector_type(8)));
typedef float f32x4  __attribute__((ext_vector_type(4)));

#define CD 192
#define NHEADS 6

// One fragment convention for BOTH A and B operands of mfma_f32_16x16x32_bf16:
// lane l supplies (row/col) = r0 + (l&15), k = k0 + 8*(l>>4) + j  (8 contiguous bf16 = 16B).
__device__ __forceinline__ bf16x8 ld_frag(const bf16* p, int r0, int k0, int ld) {
  const int l = threadIdx.x & 63;
  return *reinterpret_cast<const bf16x8*>(p + (r0 + (l & 15)) * ld + (k0 + 8 * (l >> 4)));
}

__device__ __forceinline__ f32x4 mfma16(bf16x8 a, bf16x8 b, f32x4 c) {
  return __builtin_amdgcn_mfma_f32_16x16x32_bf16(a, b, c, 0, 0, 0);
}

// tanh-approx GELU: max abs err ~1e-3.
__device__ __forceinline__ float gelu_f(float v) {
  return v / (1.f + __expf(-1.5957691216057308f * (v + 0.044715f * v * v * v)));
}

// ---------------- weight pack: fragment-major layout --------------------------------------
__global__ void prep_pack(const float* __restrict__ src, bf16* __restrict__ dst, int K, int N) {
  const int t = blockIdx.x * 256 + threadIdx.x;
  const int ktiles = K >> 5;
  const int total = (N >> 4) * ktiles * 64;
  if (t >= total) return;
  const int l  = t & 63;
  const int r  = t >> 6;
  const int kt = r % ktiles;
  const int ng = r / ktiles;
  const int n  = ng * 16 + (l & 15);
  const int k0 = kt * 32 + 8 * (l >> 4);
  bf16x8 v;
  #pragma unroll
  for (int j = 0; j < 8; ++j) v[j] = (bf16)src[(size_t)(k0 + j) * N + n];
  *(reinterpret_cast<bf16x8*>(dst) + t) = v;
}

// ---------------- fused rel-bias + shift-mask table: bm[4][6][64][64] fp32 ----------------
__global__ void prep_bm(const float* __restrict__ relb, float* __restrict__ bm) {
  const int idx = blockIdx.x * 256 + threadIdx.x;
  if (idx >= 4 * 6 * 64 * 64) return;
  const int k = idx & 63;
  const int r = (idx >> 6) & 63;
  const int h = (idx >> 12) % 6;
  const int c = idx / (4096 * 6);
  float v = -3000.f;
  if (r < 49 && k < 49) {
    const int rh = r / 7, rw = r % 7, kh = k / 7, kw = k % 7;
    const int crh = (c & 2) ? (rh < 4 ? 1 : 2) : 0;
    const int crw = (c & 1) ? (rw < 4 ? 1 : 2) : 0;
    const int ckh = (c & 2) ? (kh < 4 ? 1 : 2) : 0;
    const int ckw = (c & 1) ? (kw < 4 ? 1 : 2) : 0;
    const float mask = (crh == ckh && crw == ckw) ? 0.f : -100.f;
    v = relb[((rh - kh + 6) * 13 + (rw - kw + 6)) * 6 + h] + mask;
  }
  bm[idx] = v;
}

// ---------------- fully fused Swin block: 1 block = 1 window, 12 waves ---------------------
// Phases: LN1 -> QKV -> scores+softmax -> PV -> proj -> x2=proj+res -> LN2 -> MLP -> out.
// LDS regions phase-aliased; d_out written exactly once.
__global__ __launch_bounds__(768, 1)
void swin_block_kernel(const float* __restrict__ x,
                       const float* __restrict__ n1w, const float* __restrict__ n1b,
                       const bf16* __restrict__ wqf, const float* __restrict__ qkvb,
                       const bf16* __restrict__ wpf, const float* __restrict__ projb,
                       const float* __restrict__ bm,
                       const float* __restrict__ n2w, const float* __restrict__ n2b,
                       const bf16* __restrict__ w1f, const float* __restrict__ fb1,
                       const bf16* __restrict__ w2f, const float* __restrict__ fb2,
                       float* __restrict__ out)
{
  // region U (55.3KB): sA [64][200] -> sP[head][64][72] -> sAO [64][200] -> sA2 [64][200]
  __shared__ alignas(16) bf16 sU[NHEADS * 64 * 72];
  // region QK (61.4KB): per head Q[64][40],K[64][40] -> sX2 fp32 [64][196]
  __shared__ alignas(16) bf16 sQK[NHEADS * 2 * 64 * 40];
  // region V (27.6KB): per head V^T [32][72] -> sH [64][200]
  __shared__ alignas(16) bf16 sV[NHEADS * 32 * 72];

  const int l    = threadIdx.x & 63;
  const int wv   = threadIdx.x >> 6;     // 0..11
  const int h    = wv >> 1;              // head (attn) == col-tile ct (mlp)
  const int half = wv & 1;               // row-half
  const int r0w  = half * 32;
  const int b  = blockIdx.x >> 6;
  const int wi = blockIdx.x & 63;
  const int wh = wi >> 3, ww = wi & 7;
  const int cw = ((wh == 7) ? 2 : 0) + ((ww == 7) ? 1 : 0);

  bf16* sA  = sU;                       // [64][200]
  bf16* sQ  = sQK + h * 5120;           // [64][40]
  bf16* sK  = sQK + h * 5120 + 2560;    // [64][40]
  bf16* sVT = sV  + h * 2304;           // [32][72]
  float* sX2 = reinterpret_cast<float*>(sQK);  // [64][196]
  bf16* sH  = sV;                       // [64][200]

  // ---- LN1 with shifted-window gather ----
  {
    const float w0 = n1w[l], w1 = n1w[l + 64], w2 = n1w[l + 128];
    const float c0 = n1b[l], c1 = n1b[l + 64], c2 = n1b[l + 128];
    for (int t = wv; t < 49; t += 12) {
      const int th = t / 7, tw = t - 7 * th;
      const int ho = (wh * 7 + th + 3) % 56;
      const int wo = (ww * 7 + tw + 3) % 56;
      const float* xr = x + ((size_t)b * 3136 + ho * 56 + wo) * CD;
      float v0 = xr[l], v1 = xr[l + 64], v2 = xr[l + 128];
      float s  = v0 + v1 + v2;
      float ss = v0 * v0 + v1 * v1 + v2 * v2;
      #pragma unroll
      for (int off = 32; off; off >>= 1) { s += __shfl_xor(s, off); ss += __shfl_xor(ss, off); }
      const float mean = s * (1.f / 192.f);
      const float inv  = rsqrtf(ss * (1.f / 192.f) - mean * mean + 1e-5f);
      sA[t * 200 + l]       = (bf16)((v0 - mean) * inv * w0 + c0);
      sA[t * 200 + l + 64]  = (bf16)((v1 - mean) * inv * w1 + c1);
      sA[t * 200 + l + 128] = (bf16)((v2 - mean) * inv * w2 + c2);
    }
    for (int i = threadIdx.x; i < 15 * 200; i += 768) sA[49 * 200 + i] = (bf16)0.f;
  }
  __syncthreads();   // B1: sA ready

  // ---- bm prefetch (latency hidden under QKV MFMAs) ----
  float bmreg[2][4][4];
  {
    const float* bmb = bm + ((size_t)(cw * 6 + h) << 12) + (l & 15);
    #pragma unroll
    for (int mt = 0; mt < 2; ++mt)
      #pragma unroll
      for (int i = 0; i < 4; ++i) {
        const int r = r0w + mt * 16 + (l >> 4) * 4 + i;
        #pragma unroll
        for (int nt = 0; nt < 4; ++nt)
          bmreg[mt][i][nt] = bmb[r * 64 + nt * 16];
      }
  }

  // ---- QKV: rows [r0w,+32) x head h's 96 cols ----
  {
    const bf16x8* bq = reinterpret_cast<const bf16x8*>(wqf) + l;
    f32x4 acc[6][2] = {};
    #pragma unroll
    for (int ks = 0; ks < 6; ++ks) {
      const int k0 = ks * 32;
      bf16x8 af0 = ld_frag(sA, r0w,      k0, 200);
      bf16x8 af1 = ld_frag(sA, r0w + 16, k0, 200);
      #pragma unroll
      for (int nt = 0; nt < 6; ++nt) {
        const int ng = (nt >> 1) * 12 + h * 2 + (nt & 1);
        const bf16x8 bfr = bq[(ng * 6 + ks) * 64];
        acc[nt][0] = mfma16(af0, bfr, acc[nt][0]);
        acc[nt][1] = mfma16(af1, bfr, acc[nt][1]);
      }
    }
    #pragma unroll
    for (int nt = 0; nt < 6; ++nt) {
      const int which = nt >> 1;
      const int c = (nt & 1) * 16 + (l & 15);
      const float bias = qkvb[which * 192 + h * 32 + c];
      #pragma unroll
      for (int mt = 0; mt < 2; ++mt)
        #pragma unroll
        for (int i = 0; i < 4; ++i) {
          const int r = r0w + mt * 16 + (l >> 4) * 4 + i;
          const float v = acc[nt][mt][i] + bias;
          if (which == 0)      sQ[r * 40 + c] = (bf16)(v * 0.17677669529663689f);
          else if (which == 1) sK[r * 40 + c] = (bf16)v;
          else                 sVT[c * 72 + r] = (bf16)v;
        }
    }
  }
  __syncthreads();   // B2: QKV ready; sA dead

  // ---- scores + bm + softmax -> sP ----
  bf16* sP = sU + h * (64 * 72);
  {
    f32x4 sc[2][4] = {};
    bf16x8 qf0 = ld_frag(sQ, r0w,      0, 40);
    bf16x8 qf1 = ld_frag(sQ, r0w + 16, 0, 40);
    #pragma unroll
    for (int nt = 0; nt < 4; ++nt) {
      const bf16x8 kf = ld_frag(sK, nt * 16, 0, 40);
      sc[0][nt] = mfma16(qf0, kf, sc[0][nt]);
      sc[1][nt] = mfma16(qf1, kf, sc[1][nt]);
    }
    #pragma unroll
    for (int mt = 0; mt < 2; ++mt)
      #pragma unroll
      for (int i = 0; i < 4; ++i) {
        const int r = r0w + mt * 16 + (l >> 4) * 4 + i;
        float v[4];
        #pragma unroll
        for (int nt = 0; nt < 4; ++nt) v[nt] = sc[mt][nt][i] + bmreg[mt][i][nt];
        float mx = fmaxf(fmaxf(v[0], v[1]), fmaxf(v[2], v[3]));
        #pragma unroll
        for (int off = 1; off < 16; off <<= 1) mx = fmaxf(mx, __shfl_xor(mx, off));
        float p[4], sum = 0.f;
        #pragma unroll
        for (int nt = 0; nt < 4; ++nt) { p[nt] = __expf(v[nt] - mx); sum += p[nt]; }
        #pragma unroll
        for (int off = 1; off < 16; off <<= 1) sum += __shfl_xor(sum, off);
        const float isum = 1.f / sum;
        #pragma unroll
        for (int nt = 0; nt < 4; ++nt)
          sP[r * 72 + nt * 16 + (l & 15)] = (bf16)(p[nt] * isum);
      }
  }

  // ---- PV ----
  f32x4 o[2][2] = {};
  #pragma unroll
  for (int ks = 0; ks < 2; ++ks) {
    const int k0 = ks * 32;
    bf16x8 pf0 = ld_frag(sP, r0w,      k0, 72);
    bf16x8 pf1 = ld_frag(sP, r0w + 16, k0, 72);
    #pragma unroll
    for (int nt = 0; nt < 2; ++nt) {
      const bf16x8 vf = ld_frag(sVT, nt * 16, k0, 72);
      o[0][nt] = mfma16(pf0, vf, o[0][nt]);
      o[1][nt] = mfma16(pf1, vf, o[1][nt]);
    }
  }
  __syncthreads();   // B3: PV done -> sAO may overwrite sP; sQK/sV dead

  bf16* sAO = sU;    // [64][200]
  #pragma unroll
  for (int nt = 0; nt < 2; ++nt) {
    const int c = h * 32 + nt * 16 + (l & 15);
    #pragma unroll
    for (int mt = 0; mt < 2; ++mt)
      #pragma unroll
      for (int i = 0; i < 4; ++i) {
        const int r = r0w + mt * 16 + (l >> 4) * 4 + i;
        sAO[r * 200 + c] = (bf16)o[mt][nt][i];
      }
  }
  __syncthreads();   // B4: attnout ready

  // ---- proj ----
  f32x4 po[2][2] = {};
  {
    const bf16x8* bp = reinterpret_cast<const bf16x8*>(wpf) + l;
    #pragma unroll
    for (int ks = 0; ks < 6; ++ks) {
      const int k0 = ks * 32;
      bf16x8 af0 = ld_frag(sAO, r0w,      k0, 200);
      bf16x8 af1 = ld_frag(sAO, r0w + 16, k0, 200);
      #pragma unroll
      for (int nt = 0; nt < 2; ++nt) {
        const bf16x8 bfr = bp[((h * 2 + nt) * 6 + ks) * 64];
        po[0][nt] = mfma16(af0, bfr, po[0][nt]);
        po[1][nt] = mfma16(af1, bfr, po[1][nt]);
      }
    }
  }

  // ---- x2 = proj + projb + residual(x) -> sX2 (fp32, region QK; dead since B3) ----
  #pragma unroll
  for (int nt = 0; nt < 2; ++nt) {
    const int c = h * 32 + nt * 16 + (l & 15);
    const float bias = projb[c];
    #pragma unroll
    for (int mt = 0; mt < 2; ++mt)
      #pragma unroll
      for (int i = 0; i < 4; ++i) {
        const int r = r0w + mt * 16 + (l >> 4) * 4 + i;
        float xv = 0.f;
        if (r < 49) {
          const int th = r / 7, tw = r - 7 * th;
          const int ho = (wh * 7 + th + 3) % 56;
          const int wo = (ww * 7 + tw + 3) % 56;
          xv = x[((size_t)b * 3136 + ho * 56 + wo) * CD + c];
        }
        sX2[r * 196 + c] = po[mt][nt][i] + bias + xv;
      }
  }
  __syncthreads();   // B5: sX2 ready; all proj reads of sAO done

  // ---- LN2: sX2 -> sA2 (bf16, region U) ----
  bf16* sA2 = sU;
  {
    const float w0 = n2w[l], w1 = n2w[l + 64], w2 = n2w[l + 128];
    const float c0 = n2b[l], c1 = n2b[l + 64], c2 = n2b[l + 128];
    for (int t = wv; t < 64; t += 12) {
      float v0 = sX2[t * 196 + l], v1 = sX2[t * 196 + l + 64], v2 = sX2[t * 196 + l + 128];
      float s  = v0 + v1 + v2;
      float ss = v0 * v0 + v1 * v1 + v2 * v2;
      #pragma unroll
      for (int off = 32; off; off >>= 1) { s += __shfl_xor(s, off); ss += __shfl_xor(ss, off); }
      const float mean = s * (1.f / 192.f);
      const float inv  = rsqrtf(ss * (1.f / 192.f) - mean * mean + 1e-5f);
      sA2[t * 200 + l]       = (bf16)((v0 - mean) * inv * w0 + c0);
      sA2[t * 200 + l + 64]  = (bf16)((v1 - mean) * inv * w1 + c1);
      sA2[t * 200 + l + 128] = (bf16)((v2 - mean) * inv * w2 + c2);
    }
  }
  __syncthreads();   // B6: sA2 ready

  // ---- MLP: 4 chunks of 192 hidden; wave = (ct=h, rh=half); FC2 accum in VGPRs ----
  f32x4 oacc[2][2] = {};
  {
    const bf16x8* w1p = reinterpret_cast<const bf16x8*>(w1f) + l;
    const bf16x8* w2p = reinterpret_cast<const bf16x8*>(w2f) + l;
    for (int kc = 0; kc < 4; ++kc) {
      // FC1: cols kc*192 + h*32 + nt*16, rows [r0w,+32)
      {
        f32x4 acc[2][2] = {};
        #pragma unroll
        for (int ks = 0; ks < 6; ++ks) {
          const int k0 = ks * 32;
          bf16x8 af0 = ld_frag(sA2, r0w,      k0, 200);
          bf16x8 af1 = ld_frag(sA2, r0w + 16, k0, 200);
          #pragma unroll
          for (int nt = 0; nt < 2; ++nt) {
            const int ng = kc * 12 + h * 2 + nt;
            const bf16x8 bfr = w1p[(ng * 6 + ks) * 64];
            acc[0][nt] = mfma16(af0, bfr, acc[0][nt]);
            acc[1][nt] = mfma16(af1, bfr, acc[1][nt]);
          }
        }
        #pragma unroll
        for (int nt = 0; nt < 2; ++nt) {
          const int col = h * 32 + nt * 16 + (l & 15);
          const float bias = fb1[kc * 192 + col];
          #pragma unroll
          for (int mt = 0; mt < 2; ++mt)
            #pragma unroll
            for (int i = 0; i < 4; ++i) {
              const int r = r0w + mt * 16 + (l >> 4) * 4 + i;
              sH[r * 200 + col] = (bf16)gelu_f(acc[mt][nt][i] + bias);
            }
        }
      }
      __syncthreads();   // sH chunk ready
      // FC2: k-tiles kc*6+ks; out cols h*32 + nt*16
      #pragma unroll
      for (int ks = 0; ks < 6; ++ks) {
        const int k0 = ks * 32;
        bf16x8 af0 = ld_frag(sH, r0w,      k0, 200);
        bf16x8 af1 = ld_frag(sH, r0w + 16, k0, 200);
        #pragma unroll
        for (int nt = 0; nt < 2; ++nt) {
          const int ng = h * 2 + nt;
          const bf16x8 bfr = w2p[(ng * 24 + kc * 6 + ks) * 64];
          oacc[0][nt] = mfma16(af0, bfr, oacc[0][nt]);
          oacc[1][nt] = mfma16(af1, bfr, oacc[1][nt]);
        }
      }
      __syncthreads();   // FC2 reads done -> next chunk may overwrite sH
    }
  }

  // ---- final: sX2 += mlp + fb2 (wave-disjoint), then contiguous row writeout ----
  #pragma unroll
  for (int nt = 0; nt < 2; ++nt) {
    const int col = h * 32 + nt * 16 + (l & 15);
    const float bias = fb2[col];
    #pragma unroll
    for (int mt = 0; mt < 2; ++mt)
      #pragma unroll
      for (int i = 0; i < 4; ++i) {
        const int r = r0w + mt * 16 + (l >> 4) * 4 + i;
        sX2[r * 196 + col] += oacc[mt][nt][i] + bias;
      }
  }
  __syncthreads();   // B-final

  for (int r = wv; r < 49; r += 12) {
    const int th = r / 7, tw = r - 7 * th;
    const int ho = (wh * 7 + th + 3) % 56;
    const int wo = (ww * 7 + tw + 3) % 56;
    const size_t base = ((size_t)b * 3136 + ho * 56 + wo) * CD;
    out[base + l]       = sX2[r * 196 + l];
    out[base + l + 64]  = sX2[r * 196 + l + 64];
    out[base + l + 128] = sX2[r * 196 + l + 128];
  }
}

extern "C" void kernel_launch(void* const* d_in, const int* in_sizes, int n_in,
                              void* d_out, int out_size, void* d_ws, size_t ws_size,
                              hipStream_t stream) {
  const float* x     = (const float*)d_in[0];
  const float* n1w   = (const float*)d_in[1];
  const float* n1b   = (const float*)d_in[2];
  const float* qkvw  = (const float*)d_in[3];
  const float* qkvb  = (const float*)d_in[4];
  const float* projw = (const float*)d_in[5];
  const float* projb = (const float*)d_in[6];
  const float* relb  = (const float*)d_in[7];
  const float* n2w   = (const float*)d_in[8];
  const float* n2b   = (const float*)d_in[9];
  const float* f1w   = (const float*)d_in[10];
  const float* f1b   = (const float*)d_in[11];
  const float* f2w   = (const float*)d_in[12];
  const float* f2b   = (const float*)d_in[13];

  char* ws = (char*)d_ws;
  bf16*  wqf = (bf16*)(ws + 0);        // qkv packed: 221184 B
  bf16*  wpf = (bf16*)(ws + 221184);   // proj packed: 73728 B
  bf16*  w1f = (bf16*)(ws + 294912);   // fc1 packed: 294912 B
  bf16*  w2f = (bf16*)(ws + 589824);   // fc2 packed: 294912 B
  float* bm  = (float*)(ws + 884736);  // bias+mask table: 393216 B

  prep_pack<<<(36 * 6 * 64 + 255) / 256, 256, 0, stream>>>(qkvw, wqf, 192, 576);
  prep_pack<<<(12 * 6 * 64 + 255) / 256, 256, 0, stream>>>(projw, wpf, 192, 192);
  prep_pack<<<(48 * 6 * 64 + 255) / 256, 256, 0, stream>>>(f1w, w1f, 192, 768);
  prep_pack<<<(12 * 24 * 64 + 255) / 256, 256, 0, stream>>>(f2w, w2f, 768, 192);
  prep_bm<<<(4 * 6 * 64 * 64 + 255) / 256, 256, 0, stream>>>(relb, bm);

  swin_block_kernel<<<4096, 768, 0, stream>>>(x, n1w, n1b, wqf, qkvb, wpf, projb, bm,
                                              n2w, n2b, w1f, f1b, w2f, f2b, (float*)d_out);
}